// Round 13
// baseline (296.592 us; speedup 1.0000x reference)
//
#include <hip/hip_runtime.h>
#include <math.h>

// Problem constants: B=512, C=50000, D=256.
#define D_DIM 256
#define GTM 64    // gemm tile M
#define GTN 64    // gemm tile N
#define BK 32     // K-tile depth (bf16); 8 K-iterations
#define NB 782    // n-blocks (50000/64 rounded up)
#define NBP 784   // padded partial stride

typedef __attribute__((ext_vector_type(8))) short short8;
typedef __attribute__((ext_vector_type(4))) float floatx4;
typedef unsigned long long u64;

__device__ __forceinline__ unsigned short f2bf(float f) {
    unsigned int u = __float_as_uint(f);
    u += 0x7FFFu + ((u >> 16) & 1u);   // round-to-nearest-even
    return (unsigned short)(u >> 16);
}

__device__ __forceinline__ short8 pack8(float4 x, float4 y) {
    short8 r;
    r[0] = (short)f2bf(x.x); r[1] = (short)f2bf(x.y);
    r[2] = (short)f2bf(x.z); r[3] = (short)f2bf(x.w);
    r[4] = (short)f2bf(y.x); r[5] = (short)f2bf(y.y);
    r[6] = (short)f2bf(y.z); r[7] = (short)f2bf(y.w);
    return r;
}

// ---- kernel 1 (tiny): loadedmask via binary search over sorted ids + zero scratch --
__global__ void prep_mask(const int* __restrict__ ids, u64* __restrict__ loadedmask,
                          float* __restrict__ gaccum, unsigned int* __restrict__ gcount,
                          int n_loaded, int WPR) {
    int t = blockIdx.x * 256 + threadIdx.x;
    if (t == 0) { *gcount = 0u; *gaccum = 0.f; }
    if (t < WPR) {
        int base = t << 6;
        int lo = 0, hi = n_loaded;
        while (lo < hi) { int mid = (lo + hi) >> 1; if (ids[mid] < base) lo = mid + 1; else hi = mid; }
        u64 m = 0;
        for (int i = lo; i < n_loaded; ++i) {
            int v = ids[i]; if (v >= base + 64) break;
            m |= 1ull << (v - base);
        }
        loadedmask[t] = m;
    }
}

// ---- kernel 2: fully-fused 64x64 bf16 MFMA GEMM ------------------------------------
// Raw fp32 V/T staged with inline bf16 convert; row norms computed as a staging
// side-effect (epilogue scaling == pre-normalization); label patch read in-block as
// int4 + OR-shuffle (overlaps MFMA of co-resident waves). grid (8, 782), m fastest.
__global__ __launch_bounds__(256) void gemm_fused(
    const float* __restrict__ V, const float* __restrict__ T,
    const int* __restrict__ label, const u64* __restrict__ loadedmask,
    float* __restrict__ denomP, float* __restrict__ posP, float* __restrict__ npP,
    int C, int WPR) {
    __shared__ unsigned short As[GTM * BK];   // 4 KB bf16 [row][32]
    __shared__ unsigned short Bs[GTN * BK];   // 4 KB
    __shared__ u64 smask[GTM];                // raw label bits per tile row
    __shared__ float sInvA[GTM], sInvB[GTN];
    __shared__ float sDen[GTM], sPos[GTM], sNp[GTM];

    const int tid  = threadIdx.x;
    const int lane = tid & 63;
    const int w    = tid >> 6;
    const int m0 = blockIdx.x * GTM;
    const int n0 = blockIdx.y * GTN;

    if (tid < GTM) { sDen[tid] = 0.f; sPos[tid] = 0.f; sNp[tid] = 0.f; }

    // ---- label phase: wave w covers rows [w*16, w*16+16). int4 = 4 cols/lane;
    // 16 lanes * 4 cols = 64 cols per row; quad (lane>>4) owns one row per phase.
    {
        const int cg = (lane & 15) * 4;                  // col group within the 64
        int colbase = n0 + cg;
        if (colbase > C - 4) colbase = C - 4;            // clamp (masked via loadedw)
        int4 q[4];
        #pragma unroll
        for (int p = 0; p < 4; ++p) {                    // 4 x 16B loads in flight
            int r = m0 + w * 16 + (lane >> 4) + p * 4;
            q[p] = *(const int4*)(label + (size_t)r * C + colbase);
        }
        #pragma unroll
        for (int p = 0; p < 4; ++p) {
            unsigned int nib = (q[p].x ? 1u : 0u) | (q[p].y ? 2u : 0u) |
                               (q[p].z ? 4u : 0u) | (q[p].w ? 8u : 0u);
            u64 wv = (u64)nib << cg;
            wv |= __shfl_xor(wv, 1);                     // OR across the 16-lane quad
            wv |= __shfl_xor(wv, 2);
            wv |= __shfl_xor(wv, 4);
            wv |= __shfl_xor(wv, 8);
            if ((lane & 15) == 0) smask[w * 16 + (lane >> 4) + p * 4] = wv;
        }
    }

    // ---- staging addresses: 4 consecutive lanes share a row (kq = k-chunk)
    const int sra = lane >> 2;
    const int kq  = lane & 3;
    const int kc  = kq * 8;
    int ga = m0 + w * 16 + sra;
    int gb = n0 + w * 16 + sra;
    if (gb >= C) gb = C - 1;            // clamped; masked in epilogue
    const float* gA = V + (size_t)ga * D_DIM + kc;
    const float* gB = T + (size_t)gb * D_DIM + kc;
    unsigned short* lA = &As[(w * 16 + sra) * BK + kc];
    unsigned short* lB = &Bs[(w * 16 + sra) * BK + kc];

    // ---- compute mapping: 2x2 waves, each 32x32 via 2x2 frags of 16x16x32
    const int wm = (w >> 1) * 32;
    const int wn = (w & 1) * 32;
    const int fr = lane & 15;
    const int quad = lane >> 4;

    floatx4 acc[2][2];
    #pragma unroll
    for (int mi = 0; mi < 2; mi++)
        #pragma unroll
        for (int ni = 0; ni < 2; ni++) acc[mi][ni] = (floatx4)0.f;

    float ssA = 0.f, ssB = 0.f;         // per-lane sum-of-squares (norm side-effect)

    #pragma unroll
    for (int kt = 0; kt < D_DIM / BK; ++kt) {
        float4 a0 = *(const float4*)(gA + kt * BK);
        float4 a1 = *(const float4*)(gA + kt * BK + 4);
        float4 b0 = *(const float4*)(gB + kt * BK);
        float4 b1 = *(const float4*)(gB + kt * BK + 4);
        if (kt) __syncthreads();        // previous iter's frag reads done
        ssA += a0.x*a0.x + a0.y*a0.y + a0.z*a0.z + a0.w*a0.w
             + a1.x*a1.x + a1.y*a1.y + a1.z*a1.z + a1.w*a1.w;
        ssB += b0.x*b0.x + b0.y*b0.y + b0.z*b0.z + b0.w*b0.w
             + b1.x*b1.x + b1.y*b1.y + b1.z*b1.z + b1.w*b1.w;
        *(short8*)lA = pack8(a0, a1);   // raw bf16 (scaling deferred to epilogue)
        *(short8*)lB = pack8(b0, b1);
        __syncthreads();
        short8 af[2], bf[2];
        #pragma unroll
        for (int mi = 0; mi < 2; mi++)
            af[mi] = *(const short8*)&As[(wm + mi * 16 + fr) * BK + quad * 8];
        #pragma unroll
        for (int ni = 0; ni < 2; ni++)
            bf[ni] = *(const short8*)&Bs[(wn + ni * 16 + fr) * BK + quad * 8];
        #pragma unroll
        for (int mi = 0; mi < 2; mi++)
            #pragma unroll
            for (int ni = 0; ni < 2; ni++)
                acc[mi][ni] = __builtin_amdgcn_mfma_f32_16x16x32_bf16(
                    af[mi], bf[ni], acc[mi][ni], 0, 0, 0);
    }

    // ---- norms: reduce ss across the 4 lanes sharing each row
    ssA += __shfl_xor(ssA, 1); ssA += __shfl_xor(ssA, 2);
    ssB += __shfl_xor(ssB, 1); ssB += __shfl_xor(ssB, 2);
    if (kq == 0) {
        sInvA[w * 16 + sra] = 1.0f / sqrtf(ssA);             // visual: no eps
        sInvB[w * 16 + sra] = 1.0f / (1e-6f + sqrtf(ssB));   // text: +1e-6 on norm
    }
    __syncthreads();

    // ---- epilogue: D layout row = quad*4 + reg, col = lane&15 per 16x16 frag.
    const u64 loadedw = loadedmask[n0 >> 6];  // block's 64-col window = one word
    #pragma unroll
    for (int mi = 0; mi < 2; mi++) {
        #pragma unroll
        for (int i = 0; i < 4; i++) {
            const int mloc = wm + mi * 16 + quad * 4 + i;
            const float invA = sInvA[mloc];
            const u64 praw = smask[mloc];
            const u64 posw = praw & loadedw;
            const u64 negw = loadedw & ~praw;
            float den = 0.f, pos = 0.f, np = 0.f;
            #pragma unroll
            for (int ni = 0; ni < 2; ni++) {
                const int nloc = wn + ni * 16 + fr;
                const float s = acc[mi][ni][i] * invA * sInvB[nloc];
                if ((negw >> nloc) & 1) den += __expf(s);
                if ((posw >> nloc) & 1) { pos += s; np += 1.f; }
            }
            #pragma unroll
            for (int off = 8; off >= 1; off >>= 1) {   // reduce 16-lane quad row
                den += __shfl_xor(den, off);
                pos += __shfl_xor(pos, off);
                np  += __shfl_xor(np, off);
            }
            if (fr == 0) {
                if (den != 0.f) atomicAdd(&sDen[mloc], den);
                if (np  != 0.f) { atomicAdd(&sPos[mloc], pos); atomicAdd(&sNp[mloc], np); }
            }
        }
    }
    __syncthreads();
    if (tid < GTM) {   // row-major partials: [row][n-block] for coalesced reduce
        denomP[(size_t)(m0 + tid) * NBP + blockIdx.y] = sDen[tid];
        posP[(size_t)(m0 + tid) * NBP + blockIdx.y]   = sPos[tid];
        npP[(size_t)(m0 + tid) * NBP + blockIdx.y]    = sNp[tid];
    }
}

// ---- kernel 3: reduce rows + last-block computes the final mean ---------------------
__global__ void reduce_rows(const float* __restrict__ denomP, const float* __restrict__ posP,
                            const float* __restrict__ npP,
                            float* __restrict__ gaccum, unsigned int* __restrict__ gcount,
                            float* __restrict__ out, int B) {
    __shared__ float bsum[4];
    int wv   = threadIdx.x >> 6;
    int row  = blockIdx.x * 4 + wv;
    int lane = threadIdx.x & 63;
    float den = 0.f, pos = 0.f, np = 0.f;
    if (row < B) {
        for (int bn = lane; bn < NB; bn += 64) {   // contiguous within row: coalesced
            den += denomP[(size_t)row * NBP + bn];
            pos += posP[(size_t)row * NBP + bn];
            np  += npP[(size_t)row * NBP + bn];
        }
        #pragma unroll
        for (int off = 32; off > 0; off >>= 1) {
            den += __shfl_xor(den, off);
            pos += __shfl_xor(pos, off);
            np  += __shfl_xor(np, off);
        }
    }
    if (lane == 0) bsum[wv] = (row < B) ? (logf(den) - pos / np) : 0.f;
    __syncthreads();
    if (threadIdx.x == 0) {
        float s = bsum[0] + bsum[1] + bsum[2] + bsum[3];
        atomicAdd(gaccum, s);            // 128 ops total: contention negligible
        __threadfence();
        unsigned int old = atomicAdd(gcount, 1u);
        if (old == gridDim.x - 1) {      // last block: all adds complete & visible
            float tot = atomicAdd(gaccum, 0.0f);   // atomic read-back
            out[0] = tot / (float)B;
        }
    }
}

extern "C" void kernel_launch(void* const* d_in, const int* in_sizes, int n_in,
                              void* d_out, int out_size, void* d_ws, size_t ws_size,
                              hipStream_t stream) {
    const float* V     = (const float*)d_in[0];
    const float* T     = (const float*)d_in[1];
    const int*   label = (const int*)d_in[2];
    const int*   ids   = (const int*)d_in[3];
    int B = in_sizes[0] / D_DIM;   // 512
    int C = in_sizes[1] / D_DIM;   // 50000
    int n_loaded = in_sizes[3];    // 40000
    int WPR = (C + 63) >> 6;       // mask words per row (782)

    // ws layout (bytes):
    //   0        : gaccum [1 f], gcount [1 u32]    (pad to 2048)
    //   2048     : loadedmask [782 u64]            (ends 8304; pad to 8320)
    //   8320     : denomP [512*784 f]              (1,605,632 -> ends 1,613,952)
    //   1613952  : posP                            (ends 3,219,584)
    //   3219584  : npP                             (ends 4,825,216)
    char* ws = (char*)d_ws;
    float*        gaccum = (float*)(ws + 0);
    unsigned int* gcount = (unsigned int*)(ws + 8);
    u64*   loadedmask = (u64*)(ws + 2048);
    float* denomP  = (float*)(ws + 8320);
    float* posP    = (float*)(ws + 1613952);
    float* npP     = (float*)(ws + 3219584);

    prep_mask<<<(WPR + 255) / 256, 256, 0, stream>>>(
        ids, loadedmask, gaccum, gcount, n_loaded, WPR);

    dim3 grid(B / GTM, NB);   // m fastest: 8 blocks share one T-tile
    gemm_fused<<<grid, 256, 0, stream>>>(V, T, label, loadedmask,
                                         denomP, posP, npP, C, WPR);

    reduce_rows<<<(B + 3) / 4, 256, 0, stream>>>(denomP, posP, npP,
                                                 gaccum, gcount, (float*)d_out, B);
}